// Round 7
// baseline (456.991 us; speedup 1.0000x reference)
//
#include <hip/hip_runtime.h>
#include <stdint.h>

// ---------------------------------------------------------------------------
// SchNetLayer on MI355X (gfx950).
// I/O: float tensors f32, indices int32. Internal: bf16 MFMA.
//
// R2: atomic scatter (100M f32 atomics) = atomic-rate bound -> counting sort.
// R3: k_mlp1 251us @75% VALUBusy = libm softplus -> native v_exp/v_log.
// R4: k_weh latency-bound (scalar gathers + 402MB weh round-trip) -> fuse.
// R5: k_wz FETCH 132MB = midact round-trip -> fuse MLP1 into k_edge.
// R6: k_edge 201us @ 2 blocks/CU (70.7KB LDS) = occupancy-latency bound;
//     k_he/k_final at 128 blocks = 1 block/CU serialization.
//     -> R7: k_edge keeps GEMM2 A-fragments in registers (A identical for
//     both n0 halves), one 34.8KB LDS buffer recycled dist->mid->HeC,
//     launch_bounds(256,3) => 3 blocks/CU. k_he/k_final: 64x64 tiles,
//     512 blocks => 2 blocks/CU everywhere.
//
// Pipeline:
//   k_zero2: z = 0, cnt = 0
//   sort:  k_hist, k_scan, k_place        (counting sort by receiver)
//   k_prep : cast+transpose weights -> bf16 ws
//   k_he   : he = bf16(electrons) @ h_w   [8192,256] bf16   (64x64 tiles)
//   k_edge : per 128-edge tile (sorted): mid=SSP(dist[perm]@w1+b1);
//            A-frags->regs; for n0 in {0,128}: we=mid@w2; weh=we*src[snd];
//            segmented reduce by receiver run -> f32 atomics into z
//   k_final: out = electrons + bf16(z) @ g_catT   f32 out   (64x64 tiles)
// ---------------------------------------------------------------------------

#define N_ELEC 8192
#define N_NUC  512
#define EMB    256
#define KER    256
#define DF     64
#define MID    128
#define NEDGE  131072
#define RPS    8256   // rowptr per-type stride (ints)
#define CSTR   272    // LDS row stride bytes for 128-col u16 tiles (+16 pad)

using u16 = unsigned short;
typedef short short8 __attribute__((ext_vector_type(8)));
typedef float f32x4 __attribute__((ext_vector_type(4)));

__device__ __forceinline__ float bf2f(u16 h) {
  return __uint_as_float(((unsigned)h) << 16);
}
__device__ __forceinline__ u16 f2bf(float f) {
  unsigned u = __float_as_uint(f);
  return (u16)((u + 0x7FFFu + ((u >> 16) & 1u)) >> 16);  // RNE
}
__device__ __forceinline__ unsigned pkbf(float a, float b) {
  return ((unsigned)f2bf(b) << 16) | (unsigned)f2bf(a);
}
// fast shifted softplus: log(0.5 e^x + 0.5), stable, native v_exp/v_log.
__device__ __forceinline__ float ssp_fast(float x) {
  const float e = __expf(-fabsf(x));
  return fmaxf(x, 0.f) + __logf(fmaf(0.5f, e, 0.5f));
}

// ---- 64x64 tile GEMM machinery (k_he / k_final) ----------------------------
// Stage a 64x32 bf16 tile (row stride bytes) into 4 KB LDS [64][32] bf16.
__device__ __forceinline__ void stage_t64(const char* g0, long stride,
                                          char* lds, int tid) {
  const int l = tid & 63, w = tid >> 6;
  const int r = w * 16 + (l >> 2);
  const int cb = (l & 3) * 16;
  __builtin_amdgcn_global_load_lds(
      (const __attribute__((address_space(1))) unsigned*)(g0 +
                                                          (long)r * stride +
                                                          cb),
      (__attribute__((address_space(3))) unsigned*)(lds + w * 1024), 16, 0, 0);
}
// Stage a 64x32 tile of an f32 matrix into [64][32]-bf16 LDS.
__device__ __forceinline__ void stage_f64(const float* g0, int stride_e,
                                          int kt, char* lds, int tid) {
#pragma unroll
  for (int k = 0; k < 4; ++k) {
    const int idx2 = k * 256 + tid;
    const int row = idx2 >> 4, cp = idx2 & 15;
    const float2 v = *(const float2*)(g0 + (long)row * stride_e + kt + cp * 2);
    *(unsigned*)(lds + row * 64 + cp * 4) = pkbf(v.x, v.y);
  }
}
// C = A[64,K] * Bt[64,K]^T; 4 waves in 2x2 quadrants of 32x32, 2x2 frags.
template <bool A_F32>
__device__ __forceinline__ void gemm64(const char* A0, long as_bytes,
                                       const float* Af, int as_elems,
                                       const char* B0, long bs, int K,
                                       char* As, char* Bs, f32x4 acc[2][2],
                                       int tid) {
  const int l = tid & 63, lane15 = l & 15, quad = l >> 4, wv = tid >> 6;
  const int mw = (wv >> 1) * 32, nw = (wv & 1) * 32;
  for (int kt = 0; kt < K; kt += 32) {
    if (A_F32)
      stage_f64(Af, as_elems, kt, As, tid);
    else
      stage_t64(A0 + (long)kt * 2, as_bytes, As, tid);
    stage_t64(B0 + (long)kt * 2, bs, Bs, tid);
    __syncthreads();
    short8 af[2], bf[2];
#pragma unroll
    for (int i = 0; i < 2; ++i) {
      af[i] = *(const short8*)(As + (mw + i * 16 + lane15) * 64 + quad * 16);
      bf[i] = *(const short8*)(Bs + (nw + i * 16 + lane15) * 64 + quad * 16);
    }
#pragma unroll
    for (int mi = 0; mi < 2; ++mi)
#pragma unroll
      for (int ni = 0; ni < 2; ++ni)
        acc[mi][ni] = __builtin_amdgcn_mfma_f32_16x16x32_bf16(
            af[mi], bf[ni], acc[mi][ni], 0, 0, 0);
    __syncthreads();
  }
}

// --------------------------- z = 0, cnt = 0 ---------------------------------
__global__ __launch_bounds__(256) void k_zero2(float4* z, int* cnt) {
  const int b = blockIdx.x;
  if (b < 6144)
    z[b * 256 + threadIdx.x] = (float4){0.f, 0.f, 0.f, 0.f};
  else
    cnt[(b - 6144) * 256 + threadIdx.x] = 0;
}

// ----------------------------- sort kernels ---------------------------------
__global__ __launch_bounds__(256) void k_hist(const int* r0, const int* r1,
                                              const int* r2, int* cnt) {
  const int t = blockIdx.z;
  const int* rcv = t == 0 ? r0 : (t == 1 ? r1 : r2);
  const int e = blockIdx.x * 256 + threadIdx.x;
  atomicAdd(&cnt[t * N_ELEC + rcv[e]], 1);
}

__global__ __launch_bounds__(256) void k_scan(const int* cnt, int* rowptr,
                                              int* cursor) {
  const int t = blockIdx.x, tid = threadIdx.x;
  __shared__ int part[256];
  const int* c = cnt + t * N_ELEC;
  int s = 0;
#pragma unroll
  for (int i = 0; i < 32; ++i) s += c[tid * 32 + i];
  part[tid] = s;
  __syncthreads();
  for (int off = 1; off < 256; off <<= 1) {
    int v = (tid >= off) ? part[tid - off] : 0;
    __syncthreads();
    part[tid] += v;
    __syncthreads();
  }
  int run = (tid == 0) ? 0 : part[tid - 1];
  int* rp = rowptr + t * RPS;
  int* cu = cursor + t * N_ELEC;
  for (int i = 0; i < 32; ++i) {
    rp[tid * 32 + i] = run;
    cu[tid * 32 + i] = run;
    run += c[tid * 32 + i];
  }
  if (tid == 255) rp[N_ELEC] = run;  // = NEDGE
}

__global__ __launch_bounds__(256) void k_place(const int* r0, const int* r1,
                                               const int* r2, const int* s0,
                                               const int* s1, const int* s2,
                                               int* cursor, int* perm,
                                               int* snd_s, int* rcv_s) {
  const int t = blockIdx.z;
  const int* rcv = t == 0 ? r0 : (t == 1 ? r1 : r2);
  const int* snd = t == 0 ? s0 : (t == 1 ? s1 : s2);
  const int e = blockIdx.x * 256 + threadIdx.x;
  const int rr = rcv[e];
  const int pos = atomicAdd(&cursor[t * N_ELEC + rr], 1);
  perm[t * NEDGE + pos] = e;
  snd_s[t * NEDGE + pos] = snd[e];
  rcv_s[t * NEDGE + pos] = rr;
}

// ------------------ prep: f32 weights -> transposed bf16 --------------------
// hwT [KER][EMB], w1T [3][MID][DF], w2T [3][KER][MID], gT [EMB][3*KER]
__global__ __launch_bounds__(256) void k_prep(
    const float* h_w, const float* w1s, const float* w1a, const float* w1n,
    const float* w2s, const float* w2a, const float* w2n, const float* gs,
    const float* ga, const float* gn, u16* hwT, u16* w1T, u16* w2T, u16* gT) {
  int i = blockIdx.x * 256 + threadIdx.x;
  if (i < 65536) {
    int n = i >> 8, k = i & 255;
    hwT[i] = f2bf(h_w[k * 256 + n]);
    return;
  }
  int j = i - 65536;
  if (j < 24576) {
    int t = j >> 13, jj = j & 8191, n = jj >> 6, k = jj & 63;
    const float* w1 = t == 0 ? w1s : (t == 1 ? w1a : w1n);
    w1T[j] = f2bf(w1[k * 128 + n]);
    return;
  }
  j -= 24576;
  if (j < 98304) {
    int t = j >> 15, jj = j & 32767, n = jj >> 7, k = jj & 127;
    const float* w2 = t == 0 ? w2s : (t == 1 ? w2a : w2n);
    w2T[j] = f2bf(w2[k * 256 + n]);
    return;
  }
  j -= 98304;
  if (j < 196608) {
    int n = j / 768, q = j % 768, t = q >> 8, k = q & 255;
    const float* g = t == 0 ? gs : (t == 1 ? ga : gn);
    gT[j] = f2bf(g[k * 256 + n]);
  }
}

// ------------------- he = electrons @ h_w  (64x64 tiles) --------------------
__global__ __launch_bounds__(256) void k_he(const float* elec, const u16* hwT,
                                            u16* he) {
  __shared__ char As[4096], Bs[4096];
  f32x4 acc[2][2];
#pragma unroll
  for (int i = 0; i < 2; ++i)
#pragma unroll
    for (int j = 0; j < 2; ++j) acc[i][j] = (f32x4){0.f, 0.f, 0.f, 0.f};
  const int m0 = blockIdx.x * 64, n0 = blockIdx.y * 64;
  gemm64<true>(nullptr, 0, elec + (long)m0 * 256, 256,
               (const char*)hwT + (long)n0 * 512, 512, 256, As, Bs, acc,
               threadIdx.x);
  const int l = threadIdx.x & 63, lane15 = l & 15, quad = l >> 4,
            wv = threadIdx.x >> 6;
  const int mw = (wv >> 1) * 32, nw = (wv & 1) * 32;
#pragma unroll
  for (int mi = 0; mi < 2; ++mi)
#pragma unroll
    for (int r = 0; r < 4; ++r) {
      const int row = m0 + mw + mi * 16 + quad * 4 + r;
#pragma unroll
      for (int ni = 0; ni < 2; ++ni) {
        const int col = n0 + nw + ni * 16 + lane15;
        he[row * 256 + col] = f2bf(acc[mi][ni][r]);
      }
    }
}

// ---- fully fused edge kernel -----------------------------------------------
// Per 128-edge tile (receiver-sorted), ONE 34.8 KB LDS buffer recycled:
//   stage dist halves -> GEMM1 -> barrier -> write mid (SSP) -> barrier ->
//   pull GEMM2 A-frags to registers (A identical for both n0) -> barrier ->
//   for n0 in {0,128}: GEMM2(reg A, global B) -> stage he/nuc rows ->
//   in-place multiply -> segmented reduce -> f32 atomics into z.
__global__ __launch_bounds__(256, 3) void k_edge(
    const float* d0, const float* d1, const float* d2, const float* b0,
    const float* b1p, const float* b2, const u16* w1T, const u16* w2T,
    const u16* he, const float* nucf, const int* perm, const int* snd_s,
    const int* rcv_s, float* z) {
  __shared__ char buf[128 * CSTR];  // 34816 B: dist halves -> mid -> HeC
  __shared__ int snd_l[128], rcv_l[128];

  const int t = blockIdx.z;
  const int m0 = blockIdx.x * 128;
  const int tid = threadIdx.x;
  const float* dist = t == 0 ? d0 : (t == 1 ? d1 : d2);
  const float* bias = t == 0 ? b0 : (t == 1 ? b1p : b2);
  const u16* w1t = w1T + t * 8192;   // [128][64]
  const u16* w2t = w2T + t * 32768;  // [256][128]
  const bool is_nuc = (t == 2);

  // tile meta (visible after first barrier)
  if (tid < 128)
    snd_l[tid] = snd_s[t * NEDGE + m0 + tid];
  else
    rcv_l[tid - 128] = rcv_s[t * NEDGE + m0 + tid - 128];

  // stage gathered dist rows as two K-halves [128][32] bf16 (64 B rows)
  int rows[4];
  const int* pm = perm + t * NEDGE + m0;
#pragma unroll
  for (int s = 0; s < 4; ++s) rows[s] = pm[(s * 256 + tid) >> 3];
#pragma unroll
  for (int j = 0; j < 2; ++j)
#pragma unroll
    for (int s = 0; s < 4; ++s) {
      const int idx = s * 256 + tid, row = idx >> 3, ch = idx & 7;
      const float4 v =
          *(const float4*)(dist + (long)rows[s] * 64 + j * 32 + ch * 4);
      uint2 p;
      p.x = pkbf(v.x, v.y);
      p.y = pkbf(v.z, v.w);
      *(uint2*)(buf + j * 8192 + row * 64 + ch * 8) = p;
    }
  __syncthreads();

  const int l = tid & 63, lane15 = l & 15, quad = l >> 4, wv = tid >> 6;
  const int mw = (wv >> 1) * 64, nw = (wv & 1) * 64;

  // GEMM1: [128,64] @ [64,128] -> acc   (B = w1t direct from global, L2-hot)
  f32x4 acc[4][4];
#pragma unroll
  for (int i = 0; i < 4; ++i)
#pragma unroll
    for (int j = 0; j < 4; ++j) acc[i][j] = (f32x4){0.f, 0.f, 0.f, 0.f};
#pragma unroll
  for (int j = 0; j < 2; ++j) {
    short8 af[4], bf[4];
#pragma unroll
    for (int i = 0; i < 4; ++i) {
      af[i] = *(const short8*)(buf + j * 8192 + (mw + i * 16 + lane15) * 64 +
                               quad * 16);
      bf[i] = *(const short8*)(w1t + (nw + i * 16 + lane15) * 64 + j * 32 +
                               quad * 8);
    }
#pragma unroll
    for (int mi = 0; mi < 4; ++mi)
#pragma unroll
      for (int ni = 0; ni < 4; ++ni)
        acc[mi][ni] = __builtin_amdgcn_mfma_f32_16x16x32_bf16(
            af[mi], bf[ni], acc[mi][ni], 0, 0, 0);
  }
  __syncthreads();  // all waves done reading dist halves

  // bias + SSP -> mid into buf (272 B rows)
#pragma unroll
  for (int mi = 0; mi < 4; ++mi)
#pragma unroll
    for (int r = 0; r < 4; ++r) {
      const int row = mw + mi * 16 + quad * 4 + r;
#pragma unroll
      for (int ni = 0; ni < 4; ++ni) {
        const int col = nw + ni * 16 + lane15;
        const float x = acc[mi][ni][r] + bias[col];
        *(u16*)(buf + row * CSTR + col * 2) = f2bf(ssp_fast(x));
      }
    }
  __syncthreads();  // mid visible

  // pull GEMM2 A-fragments (identical for both n0 halves) into registers
  short8 afr[4][4];  // [kt/32][mi] — 64 VGPRs
#pragma unroll
  for (int j = 0; j < 4; ++j)
#pragma unroll
    for (int i = 0; i < 4; ++i)
      afr[j][i] = *(const short8*)(buf + (mw + i * 16 + lane15) * CSTR +
                                   j * 64 + quad * 16);
  __syncthreads();  // buf free for HeC

  u16* HeC = (u16*)buf;
  for (int n0 = 0; n0 < 256; n0 += 128) {
    // GEMM2: A from registers, B = w2t cols n0.. direct from global (L2-hot)
#pragma unroll
    for (int i = 0; i < 4; ++i)
#pragma unroll
      for (int j = 0; j < 4; ++j) acc[i][j] = (f32x4){0.f, 0.f, 0.f, 0.f};
#pragma unroll
    for (int j = 0; j < 4; ++j) {
      short8 bf[4];
#pragma unroll
      for (int i = 0; i < 4; ++i)
        bf[i] = *(const short8*)(w2t + (n0 + nw + i * 16 + lane15) * 128 +
                                 j * 32 + quad * 8);
#pragma unroll
      for (int mi = 0; mi < 4; ++mi)
#pragma unroll
        for (int ni = 0; ni < 4; ++ni)
          acc[mi][ni] = __builtin_amdgcn_mfma_f32_16x16x32_bf16(
              afr[j][mi], bf[ni], acc[mi][ni], 0, 0, 0);
    }

    // stage 128 src rows (cols n0..n0+128) into HeC (coalesced 16 B chunks)
    if (!is_nuc) {
#pragma unroll
      for (int c = 0; c < 8; ++c) {
        const int chunk = c * 256 + tid;  // 2048 x 16 B
        const int row = chunk >> 4, off = chunk & 15;
        const uint4 v =
            *(const uint4*)((const char*)he + (size_t)snd_l[row] * 512 +
                            n0 * 2 + off * 16);
        *(uint4*)((char*)HeC + row * CSTR + off * 16) = v;
      }
    } else {
#pragma unroll
      for (int c = 0; c < 8; ++c) {
        const int chunk = c * 256 + tid;
        const int row = chunk >> 4, off = chunk & 15;
        const char* src =
            (const char*)nucf + (size_t)snd_l[row] * 1024 + n0 * 4 + off * 32;
        const float4 a = *(const float4*)src;
        const float4 b = *(const float4*)(src + 16);
        uint4 p;
        p.x = pkbf(a.x, a.y);
        p.y = pkbf(a.z, a.w);
        p.z = pkbf(b.x, b.y);
        p.w = pkbf(b.z, b.w);
        *(uint4*)((char*)HeC + row * CSTR + off * 16) = p;
      }
    }
    __syncthreads();

    // in-place multiply (each cell owned by exactly one lane)
#pragma unroll
    for (int mi = 0; mi < 4; ++mi)
#pragma unroll
      for (int r = 0; r < 4; ++r) {
        const int row = mw + mi * 16 + quad * 4 + r;
#pragma unroll
        for (int ni = 0; ni < 4; ++ni) {
          const int col = nw + ni * 16 + lane15;
          u16* p = (u16*)((char*)HeC + row * CSTR) + col;
          *p = f2bf(acc[mi][ni][r] * bf2f(*p));
        }
      }
    __syncthreads();

    // segmented reduce: wave wv owns rows [wv*32, wv*32+32), lane owns col
    // pair; strip edges forced as segment boundaries (extra atomics only).
    {
      const int cp = l;
      const int rbeg = wv * 32, rend = rbeg + 32;
      float a0 = 0.f, a1 = 0.f;
      int cur = rcv_l[rbeg];
      for (int row = rbeg; row < rend; ++row) {
        const unsigned p =
            *(const unsigned*)((char*)HeC + row * CSTR + cp * 4);
        a0 += __uint_as_float(p << 16);
        a1 += __uint_as_float(p & 0xffff0000u);
        const int nxt = (row + 1 < rend) ? rcv_l[row + 1] : -1;
        if (nxt != cur) {
          float* zp = z + (size_t)cur * 768 + t * 256 + n0 + cp * 2;
          unsafeAtomicAdd(zp, a0);
          unsafeAtomicAdd(zp + 1, a1);
          a0 = a1 = 0.f;
          cur = nxt;
        }
      }
    }
    __syncthreads();  // HeC reused next n0
  }
}

// ------ out = electrons_f32 + bf16(z) @ gT^T  (f32, 64x64 tiles) ------------
__global__ __launch_bounds__(256) void k_final(const float* z, const u16* gT,
                                               const float* elec, float* out) {
  __shared__ char As[4096], Bs[4096];
  f32x4 acc[2][2];
#pragma unroll
  for (int i = 0; i < 2; ++i)
#pragma unroll
    for (int j = 0; j < 2; ++j) acc[i][j] = (f32x4){0.f, 0.f, 0.f, 0.f};
  const int m0 = blockIdx.x * 64, n0 = blockIdx.y * 64;
  gemm64<true>(nullptr, 0, z + (long)m0 * 768, 768,
               (const char*)gT + (long)n0 * 1536, 1536, 768, As, Bs, acc,
               threadIdx.x);
  const int l = threadIdx.x & 63, lane15 = l & 15, quad = l >> 4,
            wv = threadIdx.x >> 6;
  const int mw = (wv >> 1) * 32, nw = (wv & 1) * 32;
#pragma unroll
  for (int mi = 0; mi < 2; ++mi)
#pragma unroll
    for (int r = 0; r < 4; ++r) {
      const int row = m0 + mw + mi * 16 + quad * 4 + r;
#pragma unroll
      for (int ni = 0; ni < 2; ++ni) {
        const int col = n0 + nw + ni * 16 + lane15;
        out[row * 256 + col] = acc[mi][ni][r] + elec[row * 256 + col];
      }
    }
}

// ---------------------------------------------------------------------------
extern "C" void kernel_launch(void* const* d_in, const int* in_sizes, int n_in,
                              void* d_out, int out_size, void* d_ws,
                              size_t ws_size, hipStream_t stream) {
  int I_dist[3], I_w1[3], I_b1[3], I_w2[3], I_g[3], I_hw;
  if (in_sizes[3] == 64 * 128) {  // setup_inputs() dict order
    for (int t = 0; t < 3; ++t) {
      I_dist[t] = 2 + t * 5 + 0;
      I_w1[t] = 2 + t * 5 + 1;
      I_b1[t] = 2 + t * 5 + 2;
      I_w2[t] = 2 + t * 5 + 3;
      I_g[t] = 2 + t * 5 + 4;
    }
    I_hw = 17;
  } else {  // reference signature order
    I_dist[0] = 2; I_dist[1] = 3; I_dist[2] = 4;
    I_w1[0] = 5;  I_b1[0] = 6;  I_w2[0] = 7;
    I_w1[1] = 8;  I_b1[1] = 9;  I_w2[1] = 10;
    I_w1[2] = 11; I_b1[2] = 12; I_w2[2] = 13;
    I_g[0] = 14; I_g[1] = 15; I_g[2] = 16;
    I_hw = 17;
  }
  const int I_snd[3] = {18, 19, 20};
  const int I_rcv[3] = {21, 22, 23};

  char* ws = (char*)d_ws;
  // workspace layout (bytes). Total ~36 MB.
  u16* he = (u16*)(ws + 0);              //   4,194,304
  u16* hwT = (u16*)(ws + 4194304);       //     131,072
  u16* w1T = (u16*)(ws + 4325376);       //      49,152
  u16* w2T = (u16*)(ws + 4374528);       //     196,608
  u16* gT = (u16*)(ws + 4571136);        //     393,216
  float* z = (float*)(ws + 4964352);     //  25,165,824
  int* cnt = (int*)(ws + 30130176);      //      98,304
  int* rowptr = (int*)(ws + 30228480);   //      99,072
  int* cursor = (int*)(ws + 30327552);   //      98,304
  int* perm = (int*)(ws + 30425856);     //   1,572,864
  int* snd_s = (int*)(ws + 31998720);    //   1,572,864
  int* rcv_s = (int*)(ws + 33571584);    //   1,572,864

  const float* elec = (const float*)d_in[0];
  const float* nuc = (const float*)d_in[1];
  const int* s0 = (const int*)d_in[I_snd[0]];
  const int* s1 = (const int*)d_in[I_snd[1]];
  const int* s2 = (const int*)d_in[I_snd[2]];
  const int* r0 = (const int*)d_in[I_rcv[0]];
  const int* r1 = (const int*)d_in[I_rcv[1]];
  const int* r2 = (const int*)d_in[I_rcv[2]];

  // z = 0 (6144 blocks) + cnt = 0 (96 blocks)
  k_zero2<<<6240, 256, 0, stream>>>((float4*)z, cnt);

  // counting sort by receiver, per type
  k_hist<<<dim3(NEDGE / 256, 1, 3), 256, 0, stream>>>(r0, r1, r2, cnt);
  k_scan<<<3, 256, 0, stream>>>(cnt, rowptr, cursor);
  k_place<<<dim3(NEDGE / 256, 1, 3), 256, 0, stream>>>(r0, r1, r2, s0, s1, s2,
                                                       cursor, perm, snd_s,
                                                       rcv_s);

  k_prep<<<1504, 256, 0, stream>>>(
      (const float*)d_in[I_hw], (const float*)d_in[I_w1[0]],
      (const float*)d_in[I_w1[1]], (const float*)d_in[I_w1[2]],
      (const float*)d_in[I_w2[0]], (const float*)d_in[I_w2[1]],
      (const float*)d_in[I_w2[2]], (const float*)d_in[I_g[0]],
      (const float*)d_in[I_g[1]], (const float*)d_in[I_g[2]], hwT, w1T, w2T,
      gT);

  k_he<<<dim3(N_ELEC / 64, 4), 256, 0, stream>>>(elec, hwT, he);

  k_edge<<<dim3(NEDGE / 128, 1, 3), 256, 0, stream>>>(
      (const float*)d_in[I_dist[0]], (const float*)d_in[I_dist[1]],
      (const float*)d_in[I_dist[2]], (const float*)d_in[I_b1[0]],
      (const float*)d_in[I_b1[1]], (const float*)d_in[I_b1[2]], w1T, w2T, he,
      nuc, perm, snd_s, rcv_s, z);

  k_final<<<dim3(N_ELEC / 64, 4), 256, 0, stream>>>(z, gT, elec,
                                                    (float*)d_out);
}

// Round 8
// 404.925 us; speedup vs baseline: 1.1286x; 1.1286x over previous
//
#include <hip/hip_runtime.h>
#include <stdint.h>

// ---------------------------------------------------------------------------
// SchNetLayer on MI355X (gfx950).
// I/O: float tensors f32, indices int32. Internal: bf16 MFMA.
//
// R2: atomic scatter (100M f32 atomics) = atomic-rate bound -> counting sort.
// R3: k_mlp1 251us @75% VALUBusy = libm softplus -> native v_exp/v_log.
// R4: k_weh latency-bound (scalar gathers + 402MB weh round-trip) -> fuse.
// R5: k_wz FETCH 132MB = midact round-trip -> fuse MLP1 into k_edge.
// R6: k_edge 201us @ 2 blocks/CU (70.7KB LDS) = occupancy-latency bound.
// R7: reg A-frags + launch_bounds(256,3) SPILLED (VGPR 84<64acc+64afr;
//     FETCH+WRITE +150MB scratch traffic; 214us). Lesson: 170-VGPR cap
//     can't hold acc+afr.
// R8: 3 blocks/CU WITHOUT afr: GEMM2 A from LDS mid (ds_read, cheap);
//     HeC halved to 64 rows (multiply/reduce in two halves per n0).
//     LDS 53.25KB -> 3 blocks/CU, VGPR ~100 -> no spill.
//
// Pipeline:
//   k_setup: z=0, cnt=0, weight transposes (one dispatch)
//   sort:  k_hist, k_scan, k_place        (counting sort by receiver)
//   k_he   : he = bf16(electrons) @ h_w   [8192,256] bf16   (64x64 tiles)
//   k_edge : per 128-edge tile (sorted): mid=SSP(dist[perm]@w1+b1) in LDS;
//            for n0 in {0,128}: we=mid@w2; for half in {0,1}: stage 64
//            src rows, weh=we*src, 16-row-strip segmented reduce -> z atomics
//   k_final: out = electrons + bf16(z) @ g_catT   f32 out   (64x64 tiles)
// ---------------------------------------------------------------------------

#define N_ELEC 8192
#define N_NUC  512
#define EMB    256
#define KER    256
#define DF     64
#define MID    128
#define NEDGE  131072
#define RPS    8256   // rowptr per-type stride (ints)
#define CSTR   272    // LDS row stride bytes for 128-col u16 tiles (+16 pad)

using u16 = unsigned short;
typedef short short8 __attribute__((ext_vector_type(8)));
typedef float f32x4 __attribute__((ext_vector_type(4)));

__device__ __forceinline__ float bf2f(u16 h) {
  return __uint_as_float(((unsigned)h) << 16);
}
__device__ __forceinline__ u16 f2bf(float f) {
  unsigned u = __float_as_uint(f);
  return (u16)((u + 0x7FFFu + ((u >> 16) & 1u)) >> 16);  // RNE
}
__device__ __forceinline__ unsigned pkbf(float a, float b) {
  return ((unsigned)f2bf(b) << 16) | (unsigned)f2bf(a);
}
// fast shifted softplus: log(0.5 e^x + 0.5), stable, native v_exp/v_log.
__device__ __forceinline__ float ssp_fast(float x) {
  const float e = __expf(-fabsf(x));
  return fmaxf(x, 0.f) + __logf(fmaf(0.5f, e, 0.5f));
}

// ---- 64x64 tile GEMM machinery (k_he / k_final) ----------------------------
__device__ __forceinline__ void stage_t64(const char* g0, long stride,
                                          char* lds, int tid) {
  const int l = tid & 63, w = tid >> 6;
  const int r = w * 16 + (l >> 2);
  const int cb = (l & 3) * 16;
  __builtin_amdgcn_global_load_lds(
      (const __attribute__((address_space(1))) unsigned*)(g0 +
                                                          (long)r * stride +
                                                          cb),
      (__attribute__((address_space(3))) unsigned*)(lds + w * 1024), 16, 0, 0);
}
__device__ __forceinline__ void stage_f64(const float* g0, int stride_e,
                                          int kt, char* lds, int tid) {
#pragma unroll
  for (int k = 0; k < 4; ++k) {
    const int idx2 = k * 256 + tid;
    const int row = idx2 >> 4, cp = idx2 & 15;
    const float2 v = *(const float2*)(g0 + (long)row * stride_e + kt + cp * 2);
    *(unsigned*)(lds + row * 64 + cp * 4) = pkbf(v.x, v.y);
  }
}
template <bool A_F32>
__device__ __forceinline__ void gemm64(const char* A0, long as_bytes,
                                       const float* Af, int as_elems,
                                       const char* B0, long bs, int K,
                                       char* As, char* Bs, f32x4 acc[2][2],
                                       int tid) {
  const int l = tid & 63, lane15 = l & 15, quad = l >> 4, wv = tid >> 6;
  const int mw = (wv >> 1) * 32, nw = (wv & 1) * 32;
  for (int kt = 0; kt < K; kt += 32) {
    if (A_F32)
      stage_f64(Af, as_elems, kt, As, tid);
    else
      stage_t64(A0 + (long)kt * 2, as_bytes, As, tid);
    stage_t64(B0 + (long)kt * 2, bs, Bs, tid);
    __syncthreads();
    short8 af[2], bf[2];
#pragma unroll
    for (int i = 0; i < 2; ++i) {
      af[i] = *(const short8*)(As + (mw + i * 16 + lane15) * 64 + quad * 16);
      bf[i] = *(const short8*)(Bs + (nw + i * 16 + lane15) * 64 + quad * 16);
    }
#pragma unroll
    for (int mi = 0; mi < 2; ++mi)
#pragma unroll
      for (int ni = 0; ni < 2; ++ni)
        acc[mi][ni] = __builtin_amdgcn_mfma_f32_16x16x32_bf16(
            af[mi], bf[ni], acc[mi][ni], 0, 0, 0);
    __syncthreads();
  }
}

// ---- setup: z = 0, cnt = 0, weight transposes (single dispatch) ------------
// hwT [KER][EMB], w1T [3][MID][DF], w2T [3][KER][MID], gT [EMB][3*KER]
__global__ __launch_bounds__(256) void k_setup(
    const float* h_w, const float* w1s, const float* w1a, const float* w1n,
    const float* w2s, const float* w2a, const float* w2n, const float* gs,
    const float* ga, const float* gn, u16* hwT, u16* w1T, u16* w2T, u16* gT,
    float4* z, int* cnt) {
  const int b = blockIdx.x;
  if (b < 6144) {
    z[b * 256 + threadIdx.x] = (float4){0.f, 0.f, 0.f, 0.f};
    return;
  }
  if (b < 6240) {
    cnt[(b - 6144) * 256 + threadIdx.x] = 0;
    return;
  }
  int i = (b - 6240) * 256 + threadIdx.x;
  if (i < 65536) {
    int n = i >> 8, k = i & 255;
    hwT[i] = f2bf(h_w[k * 256 + n]);
    return;
  }
  int j = i - 65536;
  if (j < 24576) {
    int t = j >> 13, jj = j & 8191, n = jj >> 6, k = jj & 63;
    const float* w1 = t == 0 ? w1s : (t == 1 ? w1a : w1n);
    w1T[j] = f2bf(w1[k * 128 + n]);
    return;
  }
  j -= 24576;
  if (j < 98304) {
    int t = j >> 15, jj = j & 32767, n = jj >> 7, k = jj & 127;
    const float* w2 = t == 0 ? w2s : (t == 1 ? w2a : w2n);
    w2T[j] = f2bf(w2[k * 256 + n]);
    return;
  }
  j -= 98304;
  if (j < 196608) {
    int n = j / 768, q = j % 768, t = q >> 8, k = q & 255;
    const float* g = t == 0 ? gs : (t == 1 ? ga : gn);
    gT[j] = f2bf(g[k * 256 + n]);
  }
}

// ----------------------------- sort kernels ---------------------------------
__global__ __launch_bounds__(256) void k_hist(const int* r0, const int* r1,
                                              const int* r2, int* cnt) {
  const int t = blockIdx.z;
  const int* rcv = t == 0 ? r0 : (t == 1 ? r1 : r2);
  const int e = blockIdx.x * 256 + threadIdx.x;
  atomicAdd(&cnt[t * N_ELEC + rcv[e]], 1);
}

__global__ __launch_bounds__(256) void k_scan(const int* cnt, int* rowptr,
                                              int* cursor) {
  const int t = blockIdx.x, tid = threadIdx.x;
  __shared__ int part[256];
  const int* c = cnt + t * N_ELEC;
  int s = 0;
#pragma unroll
  for (int i = 0; i < 32; ++i) s += c[tid * 32 + i];
  part[tid] = s;
  __syncthreads();
  for (int off = 1; off < 256; off <<= 1) {
    int v = (tid >= off) ? part[tid - off] : 0;
    __syncthreads();
    part[tid] += v;
    __syncthreads();
  }
  int run = (tid == 0) ? 0 : part[tid - 1];
  int* rp = rowptr + t * RPS;
  int* cu = cursor + t * N_ELEC;
  for (int i = 0; i < 32; ++i) {
    rp[tid * 32 + i] = run;
    cu[tid * 32 + i] = run;
    run += c[tid * 32 + i];
  }
  if (tid == 255) rp[N_ELEC] = run;  // = NEDGE
}

__global__ __launch_bounds__(256) void k_place(const int* r0, const int* r1,
                                               const int* r2, const int* s0,
                                               const int* s1, const int* s2,
                                               int* cursor, int* perm,
                                               int* snd_s, int* rcv_s) {
  const int t = blockIdx.z;
  const int* rcv = t == 0 ? r0 : (t == 1 ? r1 : r2);
  const int* snd = t == 0 ? s0 : (t == 1 ? s1 : s2);
  const int e = blockIdx.x * 256 + threadIdx.x;
  const int rr = rcv[e];
  const int pos = atomicAdd(&cursor[t * N_ELEC + rr], 1);
  perm[t * NEDGE + pos] = e;
  snd_s[t * NEDGE + pos] = snd[e];
  rcv_s[t * NEDGE + pos] = rr;
}

// ------------------- he = electrons @ h_w  (64x64 tiles) --------------------
__global__ __launch_bounds__(256) void k_he(const float* elec, const u16* hwT,
                                            u16* he) {
  __shared__ char As[4096], Bs[4096];
  f32x4 acc[2][2];
#pragma unroll
  for (int i = 0; i < 2; ++i)
#pragma unroll
    for (int j = 0; j < 2; ++j) acc[i][j] = (f32x4){0.f, 0.f, 0.f, 0.f};
  const int m0 = blockIdx.x * 64, n0 = blockIdx.y * 64;
  gemm64<true>(nullptr, 0, elec + (long)m0 * 256, 256,
               (const char*)hwT + (long)n0 * 512, 512, 256, As, Bs, acc,
               threadIdx.x);
  const int l = threadIdx.x & 63, lane15 = l & 15, quad = l >> 4,
            wv = threadIdx.x >> 6;
  const int mw = (wv >> 1) * 32, nw = (wv & 1) * 32;
#pragma unroll
  for (int mi = 0; mi < 2; ++mi)
#pragma unroll
    for (int r = 0; r < 4; ++r) {
      const int row = m0 + mw + mi * 16 + quad * 4 + r;
#pragma unroll
      for (int ni = 0; ni < 2; ++ni) {
        const int col = n0 + nw + ni * 16 + lane15;
        he[row * 256 + col] = f2bf(acc[mi][ni][r]);
      }
    }
}

// ---- fully fused edge kernel (R8: mid in LDS + half-size HeC) --------------
// Per 128-edge tile (receiver-sorted):
//   stage dist halves into mid[0:16K] -> GEMM1 -> barrier -> SSP -> mid
//   for n0 in {0,128}:
//     GEMM2: A from mid (ds_read), B = w2t (global, L2-hot)
//     for half in {0,1}:  (rows half*64 .. half*64+64)
//       stage 64 src rows (he bf16 / nuc f32) into hc
//       multiply in place (waves with mw==half*64 own the rows)
//       16-row-strip segmented reduce -> f32 atomics into z
__global__ __launch_bounds__(256, 3) void k_edge(
    const float* d0, const float* d1, const float* d2, const float* b0,
    const float* b1p, const float* b2, const u16* w1T, const u16* w2T,
    const u16* he, const float* nucf, const int* perm, const int* snd_s,
    const int* rcv_s, float* z) {
  __shared__ char mid[128 * CSTR];  // 34816 B: dist halves -> mid
  __shared__ char hc[64 * CSTR];    // 17408 B: per-half He/weh tile
  __shared__ int snd_l[128], rcv_l[128];

  const int t = blockIdx.z;
  const int m0 = blockIdx.x * 128;
  const int tid = threadIdx.x;
  const float* dist = t == 0 ? d0 : (t == 1 ? d1 : d2);
  const float* bias = t == 0 ? b0 : (t == 1 ? b1p : b2);
  const u16* w1t = w1T + t * 8192;   // [128][64]
  const u16* w2t = w2T + t * 32768;  // [256][128]
  const bool is_nuc = (t == 2);

  // tile meta (visible after first barrier)
  if (tid < 128)
    snd_l[tid] = snd_s[t * NEDGE + m0 + tid];
  else
    rcv_l[tid - 128] = rcv_s[t * NEDGE + m0 + tid - 128];

  // stage gathered dist rows as two K-halves [128][32] bf16 into mid[0:16K]
  int rows[4];
  const int* pm = perm + t * NEDGE + m0;
#pragma unroll
  for (int s = 0; s < 4; ++s) rows[s] = pm[(s * 256 + tid) >> 3];
#pragma unroll
  for (int j = 0; j < 2; ++j)
#pragma unroll
    for (int s = 0; s < 4; ++s) {
      const int idx = s * 256 + tid, row = idx >> 3, ch = idx & 7;
      const float4 v =
          *(const float4*)(dist + (long)rows[s] * 64 + j * 32 + ch * 4);
      uint2 p;
      p.x = pkbf(v.x, v.y);
      p.y = pkbf(v.z, v.w);
      *(uint2*)(mid + j * 8192 + row * 64 + ch * 8) = p;
    }
  __syncthreads();

  const int l = tid & 63, lane15 = l & 15, quad = l >> 4, wv = tid >> 6;
  const int mw = (wv >> 1) * 64, nw = (wv & 1) * 64;

  // GEMM1: [128,64] @ [64,128] -> acc   (B = w1t direct from global, L2-hot)
  f32x4 acc[4][4];
#pragma unroll
  for (int i = 0; i < 4; ++i)
#pragma unroll
    for (int j = 0; j < 4; ++j) acc[i][j] = (f32x4){0.f, 0.f, 0.f, 0.f};
#pragma unroll
  for (int j = 0; j < 2; ++j) {
    short8 af[4], bf[4];
#pragma unroll
    for (int i = 0; i < 4; ++i) {
      af[i] = *(const short8*)(mid + j * 8192 + (mw + i * 16 + lane15) * 64 +
                               quad * 16);
      bf[i] = *(const short8*)(w1t + (nw + i * 16 + lane15) * 64 + j * 32 +
                               quad * 8);
    }
#pragma unroll
    for (int mi = 0; mi < 4; ++mi)
#pragma unroll
      for (int ni = 0; ni < 4; ++ni)
        acc[mi][ni] = __builtin_amdgcn_mfma_f32_16x16x32_bf16(
            af[mi], bf[ni], acc[mi][ni], 0, 0, 0);
  }
  __syncthreads();  // all waves done reading dist halves

  // bias + SSP -> mid (272 B rows)
#pragma unroll
  for (int mi = 0; mi < 4; ++mi)
#pragma unroll
    for (int r = 0; r < 4; ++r) {
      const int row = mw + mi * 16 + quad * 4 + r;
#pragma unroll
      for (int ni = 0; ni < 4; ++ni) {
        const int col = nw + ni * 16 + lane15;
        const float x = acc[mi][ni][r] + bias[col];
        *(u16*)(mid + row * CSTR + col * 2) = f2bf(ssp_fast(x));
      }
    }
  __syncthreads();  // mid visible to all waves

  for (int n0 = 0; n0 < 256; n0 += 128) {
    // GEMM2: A = mid (LDS), B = w2t cols n0.. (direct from global, L2-hot)
#pragma unroll
    for (int i = 0; i < 4; ++i)
#pragma unroll
      for (int j = 0; j < 4; ++j) acc[i][j] = (f32x4){0.f, 0.f, 0.f, 0.f};
#pragma unroll
    for (int kt = 0; kt < 128; kt += 32) {
      short8 af[4], bf[4];
#pragma unroll
      for (int i = 0; i < 4; ++i) {
        af[i] = *(const short8*)(mid + (mw + i * 16 + lane15) * CSTR + kt * 2 +
                                 quad * 16);
        bf[i] = *(const short8*)(w2t + (n0 + nw + i * 16 + lane15) * 128 + kt +
                                 quad * 8);
      }
#pragma unroll
      for (int mi = 0; mi < 4; ++mi)
#pragma unroll
        for (int ni = 0; ni < 4; ++ni)
          acc[mi][ni] = __builtin_amdgcn_mfma_f32_16x16x32_bf16(
              af[mi], bf[ni], acc[mi][ni], 0, 0, 0);
    }

    for (int h = 0; h < 2; ++h) {
      const int rbase = h * 64;
      // stage 64 src rows (cols n0..n0+128) into hc (coalesced 16 B chunks)
      if (!is_nuc) {
#pragma unroll
        for (int c = 0; c < 4; ++c) {
          const int chunk = c * 256 + tid;  // 1024 x 16 B
          const int row = chunk >> 4, off = chunk & 15;
          const uint4 v =
              *(const uint4*)((const char*)he +
                              (size_t)snd_l[rbase + row] * 512 + n0 * 2 +
                              off * 16);
          *(uint4*)(hc + row * CSTR + off * 16) = v;
        }
      } else {
#pragma unroll
        for (int c = 0; c < 4; ++c) {
          const int chunk = c * 256 + tid;
          const int row = chunk >> 4, off = chunk & 15;
          const char* src = (const char*)nucf +
                            (size_t)snd_l[rbase + row] * 1024 + n0 * 4 +
                            off * 32;
          const float4 a = *(const float4*)src;
          const float4 b = *(const float4*)(src + 16);
          uint4 p;
          p.x = pkbf(a.x, a.y);
          p.y = pkbf(a.z, a.w);
          p.z = pkbf(b.x, b.y);
          p.w = pkbf(b.z, b.w);
          *(uint4*)(hc + row * CSTR + off * 16) = p;
        }
      }
      __syncthreads();

      // in-place multiply: waves whose fragment rows live in this half
      if ((wv >> 1) == h) {
#pragma unroll
        for (int mi = 0; mi < 4; ++mi)
#pragma unroll
          for (int r = 0; r < 4; ++r) {
            const int lrow = mi * 16 + quad * 4 + r;  // 0..63 within half
#pragma unroll
            for (int ni = 0; ni < 4; ++ni) {
              const int col = nw + ni * 16 + lane15;
              u16* p = (u16*)(hc + lrow * CSTR) + col;
              *p = f2bf(acc[mi][ni][r] * bf2f(*p));
            }
          }
      }
      __syncthreads();

      // segmented reduce: wave wv owns 16 rows [wv*16, wv*16+16) of the
      // half; lane owns col pair. Strip edges = forced segment boundaries.
      {
        const int cp = l;
        const int rbeg = wv * 16, rend = rbeg + 16;
        float a0 = 0.f, a1 = 0.f;
        int cur = rcv_l[rbase + rbeg];
        for (int row = rbeg; row < rend; ++row) {
          const unsigned p = *(const unsigned*)(hc + row * CSTR + cp * 4);
          a0 += __uint_as_float(p << 16);
          a1 += __uint_as_float(p & 0xffff0000u);
          const int nxt = (row + 1 < rend) ? rcv_l[rbase + row + 1] : -1;
          if (nxt != cur) {
            float* zp = z + (size_t)cur * 768 + t * 256 + n0 + cp * 2;
            unsafeAtomicAdd(zp, a0);
            unsafeAtomicAdd(zp + 1, a1);
            a0 = a1 = 0.f;
            cur = nxt;
          }
        }
      }
      __syncthreads();  // hc reused next half / n0
    }
  }
}

// ------ out = electrons_f32 + bf16(z) @ gT^T  (f32, 64x64 tiles) ------------
__global__ __launch_bounds__(256) void k_final(const float* z, const u16* gT,
                                               const float* elec, float* out) {
  __shared__ char As[4096], Bs[4096];
  f32x4 acc[2][2];
#pragma unroll
  for (int i = 0; i < 2; ++i)
#pragma unroll
    for (int j = 0; j < 2; ++j) acc[i][j] = (f32x4){0.f, 0.f, 0.f, 0.f};
  const int m0 = blockIdx.x * 64, n0 = blockIdx.y * 64;
  gemm64<true>(nullptr, 0, z + (long)m0 * 768, 768,
               (const char*)gT + (long)n0 * 1536, 1536, 768, As, Bs, acc,
               threadIdx.x);
  const int l = threadIdx.x & 63, lane15 = l & 15, quad = l >> 4,
            wv = threadIdx.x >> 6;
  const int mw = (wv >> 1) * 32, nw = (wv & 1) * 32;
#pragma unroll
  for (int mi = 0; mi < 2; ++mi)
#pragma unroll
    for (int r = 0; r < 4; ++r) {
      const int row = m0 + mw + mi * 16 + quad * 4 + r;
#pragma unroll
      for (int ni = 0; ni < 2; ++ni) {
        const int col = n0 + nw + ni * 16 + lane15;
        out[row * 256 + col] = acc[mi][ni][r] + elec[row * 256 + col];
      }
    }
}

// ---------------------------------------------------------------------------
extern "C" void kernel_launch(void* const* d_in, const int* in_sizes, int n_in,
                              void* d_out, int out_size, void* d_ws,
                              size_t ws_size, hipStream_t stream) {
  int I_dist[3], I_w1[3], I_b1[3], I_w2[3], I_g[3], I_hw;
  if (in_sizes[3] == 64 * 128) {  // setup_inputs() dict order
    for (int t = 0; t < 3; ++t) {
      I_dist[t] = 2 + t * 5 + 0;
      I_w1[t] = 2 + t * 5 + 1;
      I_b1[t] = 2 + t * 5 + 2;
      I_w2[t] = 2 + t * 5 + 3;
      I_g[t] = 2 + t * 5 + 4;
    }
    I_hw = 17;
  } else {  // reference signature order
    I_dist[0] = 2; I_dist[1] = 3; I_dist[2] = 4;
    I_w1[0] = 5;  I_b1[0] = 6;  I_w2[0] = 7;
    I_w1[1] = 8;  I_b1[1] = 9;  I_w2[1] = 10;
    I_w1[2] = 11; I_b1[2] = 12; I_w2[2] = 13;
    I_g[0] = 14; I_g[1] = 15; I_g[2] = 16;
    I_hw = 17;
  }
  const int I_snd[3] = {18, 19, 20};
  const int I_rcv[3] = {21, 22, 23};

  char* ws = (char*)d_ws;
  // workspace layout (bytes). Total ~36 MB.
  u16* he = (u16*)(ws + 0);              //   4,194,304
  u16* hwT = (u16*)(ws + 4194304);       //     131,072
  u16* w1T = (u16*)(ws + 4325376);       //      49,152
  u16* w2T = (u16*)(ws + 4374528);       //     196,608
  u16* gT = (u16*)(ws + 4571136);        //     393,216
  float* z = (float*)(ws + 4964352);     //  25,165,824
  int* cnt = (int*)(ws + 30130176);      //      98,304
  int* rowptr = (int*)(ws + 30228480);   //      99,072
  int* cursor = (int*)(ws + 30327552);   //      98,304
  int* perm = (int*)(ws + 30425856);     //   1,572,864
  int* snd_s = (int*)(ws + 31998720);    //   1,572,864
  int* rcv_s = (int*)(ws + 33571584);    //   1,572,864

  const float* elec = (const float*)d_in[0];
  const float* nuc = (const float*)d_in[1];
  const int* s0 = (const int*)d_in[I_snd[0]];
  const int* s1 = (const int*)d_in[I_snd[1]];
  const int* s2 = (const int*)d_in[I_snd[2]];
  const int* r0 = (const int*)d_in[I_rcv[0]];
  const int* r1 = (const int*)d_in[I_rcv[1]];
  const int* r2 = (const int*)d_in[I_rcv[2]];

  // z=0 (6144) + cnt=0 (96) + weight transposes (1504) in one dispatch
  k_setup<<<7744, 256, 0, stream>>>(
      (const float*)d_in[I_hw], (const float*)d_in[I_w1[0]],
      (const float*)d_in[I_w1[1]], (const float*)d_in[I_w1[2]],
      (const float*)d_in[I_w2[0]], (const float*)d_in[I_w2[1]],
      (const float*)d_in[I_w2[2]], (const float*)d_in[I_g[0]],
      (const float*)d_in[I_g[1]], (const float*)d_in[I_g[2]], hwT, w1T, w2T,
      gT, (float4*)z, cnt);

  // counting sort by receiver, per type
  k_hist<<<dim3(NEDGE / 256, 1, 3), 256, 0, stream>>>(r0, r1, r2, cnt);
  k_scan<<<3, 256, 0, stream>>>(cnt, rowptr, cursor);
  k_place<<<dim3(NEDGE / 256, 1, 3), 256, 0, stream>>>(r0, r1, r2, s0, s1, s2,
                                                       cursor, perm, snd_s,
                                                       rcv_s);

  k_he<<<dim3(N_ELEC / 64, 4), 256, 0, stream>>>(elec, hwT, he);

  k_edge<<<dim3(NEDGE / 128, 1, 3), 256, 0, stream>>>(
      (const float*)d_in[I_dist[0]], (const float*)d_in[I_dist[1]],
      (const float*)d_in[I_dist[2]], (const float*)d_in[I_b1[0]],
      (const float*)d_in[I_b1[1]], (const float*)d_in[I_b1[2]], w1T, w2T, he,
      nuc, perm, snd_s, rcv_s, z);

  k_final<<<dim3(N_ELEC / 64, 4), 256, 0, stream>>>(z, gT, elec,
                                                    (float*)d_out);
}